// Round 4
// baseline (71.934 us; speedup 1.0000x reference)
//
#include <hip/hip_runtime.h>

// HistogramLoss: total = emd(hist(rgb_in),hist(rgb_ref)) + emd(hist(yuv_in),hist(yuv_ref))
// emd collapses to sum_k (64-k)*(h1_k - h2_k); bins tile [-0.05,1.05] disjointly.
//
// R4: decision path slimmed. lo_k=(f64)c_k-width, hi_k=(f64)c_k+width are EXACT
// in f64 (difference of two f32s), and t=min(u-lo,hi-u) == width-|u-c| in reals,
// so `t>0` reproduces the np-f64 in-window decision (flip prob ~1e-10/value).
// Both +-1 candidates still checked independently: f32-rounded centers create
// ~1e-7 seam overlaps/gaps where np double-counts — candidates provably straddle
// seams, so double-hits are captured. Soft part expm1(L*t) in f32 (err ~1e-11).
// float2 pixel loads; int32 weight accumulator (exact); f32 soft accumulator.
//
// R3 counters: top-5 dispatches are ALL 41us harness d_ws poison fills (268 MB
// at 82% HBM peak) — harness floor ~60us; controllable budget ~10us.

#define HW    65536             // 256*256
#define NPIX  524288            // 8 * HW pixel positions
#define BLOCK 256
#define PXT   2                 // pixels per thread (float2 loads)
#define NBLK  (NPIX / (BLOCK * PXT))   // 1024

__device__ __forceinline__ void contrib(double v, float vf,
    const double2* __restrict__ bnds, float ga, float gb, float Lf,
    int& aW, float& aE) {
  // guess g = ((v+1)*0.5 + 0.05)/step - 0.5 = v*ga + gb; true bin in {k0, k0+1}
  int k0 = __float2int_rd(fmaf(vf, ga, gb));
  double u = (v + 1.0) * 0.5;          // f64, matches np
  #pragma unroll
  for (int dk = 0; dk <= 1; ++dk) {
    int k = k0 + dk;
    if ((unsigned)k < 64u) {
      double2 lh = bnds[k];            // one ds_read_b128: {lo, hi} exact f64
      double t = fmin(u - lh.x, lh.y - u);   // == width - |u - c_k| in reals
      if (t > 0.0) {                   // act = 1.01^t > 1  <=>  t > 0
        float z = Lf * (float)t;       // z <= 8.6e-5
        int   w = 64 - k;
        aW += w;                       // exact integer part
        aE  = fmaf((float)w, fmaf(0.5f * z, z, z), aE);  // w * expm1(z)
      }
    }
  }
}

__global__ __launch_bounds__(BLOCK) void hl_partial(
    const float* __restrict__ img_in, const float* __restrict__ img_ref,
    double* __restrict__ partials) {
  __shared__ double2 bnds[64];
  __shared__ int    redW[4];
  __shared__ float  redE[4];

  // Replicate np.linspace(-0.05, 1.05, 65) in f64, then the module's f32 casts.
  const double start = -0.05;
  const double step  = (1.05 - (-0.05)) / 64.0;  // fl(1.1) / 2^6 (exact div)
  const double e1    = 1.0 * step + start;
  const double e2    = 2.0 * step + start;
  const double halfw = (e2 - e1) * 0.5;          // delta/2 in f64
  const double width = (double)(float)halfw;     // _WIDTH = float32(delta/2)
  if (threadIdx.x < 64) {
    double edge = (double)(int)threadIdx.x * step + start;
    double c = (double)(float)(edge + halfw);    // _CENTERS float32, exact in f64
    bnds[threadIdx.x] = make_double2(c - width, c + width);  // exact f64 bounds
  }
  __syncthreads();

  const float Lf = (float)log((double)1.01f);    // ln(float32(1.01))
  const float ga = (float)(0.5 / step);          // guess-only constants (f32 ok)
  const float gb = (float)(0.55 / step - 0.5);

  // f32-rounded YUV coefficients, f64 dot (matches np promotion)
  const double Y0 = (double)0.299f,    Y1 = (double)0.587f,    Y2 = (double)0.114f;
  const double U0 = (double)-0.14713f, U1 = (double)-0.28886f, U2 = (double)0.436f;
  const double V0 = (double)0.615f,    V1 = (double)-0.51499f, V2 = (double)-0.10001f;

  int   aWp = 0,  aWn = 0;      // + image / - image integer parts (exact)
  float aEp = 0.f, aEn = 0.f;   // soft parts

  // 2 consecutive pixels per thread; p even and HW even => never crosses an image
  const int p  = (blockIdx.x * BLOCK + threadIdx.x) * PXT;
  const int b  = p >> 16;
  const int hw = p & (HW - 1);
  const float* pi = img_in  + (size_t)b * (3 * HW) + hw;
  const float* pr = img_ref + (size_t)b * (3 * HW) + hw;
  float2 R0 = *(const float2*)(pi);
  float2 G0 = *(const float2*)(pi + HW);
  float2 B0 = *(const float2*)(pi + 2 * HW);
  float2 R1 = *(const float2*)(pr);
  float2 G1 = *(const float2*)(pr + HW);
  float2 B1 = *(const float2*)(pr + 2 * HW);

  #pragma unroll
  for (int i = 0; i < PXT; ++i) {
    float r0 = (i ? R0.y : R0.x), g0 = (i ? G0.y : G0.x), b0 = (i ? B0.y : B0.x);
    float r1 = (i ? R1.y : R1.x), g1 = (i ? G1.y : G1.x), b1 = (i ? B1.y : B1.x);

    // RGB
    contrib((double)r0, r0, bnds, ga, gb, Lf, aWp, aEp);
    contrib((double)g0, g0, bnds, ga, gb, Lf, aWp, aEp);
    contrib((double)b0, b0, bnds, ga, gb, Lf, aWp, aEp);
    contrib((double)r1, r1, bnds, ga, gb, Lf, aWn, aEn);
    contrib((double)g1, g1, bnds, ga, gb, Lf, aWn, aEn);
    contrib((double)b1, b1, bnds, ga, gb, Lf, aWn, aEn);

    // YUV (f64 dot feeds the decision; f32 shadow feeds the guess)
    double yi = fma(Y2, (double)b0, fma(Y1, (double)g0, Y0 * (double)r0));
    double ui = fma(U2, (double)b0, fma(U1, (double)g0, U0 * (double)r0));
    double vi = fma(V2, (double)b0, fma(V1, (double)g0, V0 * (double)r0));
    double yr = fma(Y2, (double)b1, fma(Y1, (double)g1, Y0 * (double)r1));
    double ur = fma(U2, (double)b1, fma(U1, (double)g1, U0 * (double)r1));
    double vr = fma(V2, (double)b1, fma(V1, (double)g1, V0 * (double)r1));

    contrib(yi, (float)yi, bnds, ga, gb, Lf, aWp, aEp);
    contrib(ui, (float)ui, bnds, ga, gb, Lf, aWp, aEp);
    contrib(vi, (float)vi, bnds, ga, gb, Lf, aWp, aEp);
    contrib(yr, (float)yr, bnds, ga, gb, Lf, aWn, aEn);
    contrib(ur, (float)ur, bnds, ga, gb, Lf, aWn, aEn);
    contrib(vr, (float)vr, bnds, ga, gb, Lf, aWn, aEn);
  }

  int   aW = aWp - aWn;        // exact int diff
  float aE = aEp - aEn;

  // wave(64) shuffle reduction, then cross-wave via LDS
  #pragma unroll
  for (int off = 32; off > 0; off >>= 1) {
    aW += __shfl_down(aW, off);
    aE += __shfl_down(aE, off);
  }
  int wv = threadIdx.x >> 6;
  if ((threadIdx.x & 63) == 0) { redW[wv] = aW; redE[wv] = aE; }
  __syncthreads();

  if (threadIdx.x == 0) {
    double sW = 0.0, sE = 0.0;
    #pragma unroll
    for (int w = 0; w < 4; ++w) { sW += (double)redW[w]; sE += (double)redE[w]; }
    partials[2 * blockIdx.x]     = sW;  // unconditional store: no ws init needed
    partials[2 * blockIdx.x + 1] = sE;
  }
}

__global__ __launch_bounds__(BLOCK) void hl_final(
    const double* __restrict__ partials, float* __restrict__ out) {
  __shared__ double redW[4], redE[4];
  double sW = 0.0, sE = 0.0;
  for (int b = threadIdx.x; b < NBLK; b += BLOCK) {
    sW += partials[2 * b];
    sE += partials[2 * b + 1];
  }
  #pragma unroll
  for (int off = 32; off > 0; off >>= 1) {
    sW += __shfl_down(sW, off);
    sE += __shfl_down(sE, off);
  }
  int wv = threadIdx.x >> 6;
  if ((threadIdx.x & 63) == 0) { redW[wv] = sW; redE[wv] = sE; }
  __syncthreads();
  if (threadIdx.x == 0) {
    double tW = 0.0, tE = 0.0;
    #pragma unroll
    for (int w = 0; w < 4; ++w) { tW += redW[w]; tE += redE[w]; }
    out[0] = (float)((tW + tE) * (1.0 / (double)NPIX));
  }
}

extern "C" void kernel_launch(void* const* d_in, const int* in_sizes, int n_in,
                              void* d_out, int out_size, void* d_ws, size_t ws_size,
                              hipStream_t stream) {
  const float* img_in  = (const float*)d_in[0];
  const float* img_ref = (const float*)d_in[1];
  float* out = (float*)d_out;
  double* partials = (double*)d_ws;   // 2*NBLK doubles = 16 KB

  hl_partial<<<NBLK, BLOCK, 0, stream>>>(img_in, img_ref, partials);
  hl_final<<<1, BLOCK, 0, stream>>>(partials, out);
}